// Round 12
// baseline (173.598 us; speedup 1.0000x reference)
//
#include <hip/hip_runtime.h>
#include <stdint.h>

// ENAS LSTM controller. R12: 15-hop protocol + clean VGPR residency.
//  - R11 evidence: four designs converged to ~88-107us because the critical
//    path kept ~25 dependent LLC hops (h-hops + idx-broadcast hops). R12
//    removes the idx hops: ALL wgs sample redundantly from bitwise-identical
//    y (fixed-order 8-partial sum). y-partials: 128 packed (2xf32) untagged
//    u64 words/wg, drained (syncthreads vmcnt-drain) before ONE y-ready tag
//    word (R7/R8-proven ordering). Tagged h (32 words/wg) published EARLY at
//    the gate update so consumers' next-cell dotHH overlaps the y wait.
//    => 15 hops total, no wg0 straggler.
//  - VGPR: R11's 128-reg weight ask consumed the whole budget -> spills.
//    Now only whh rows (64 VGPRs) + w1/w2 cols (32) are resident. wih is
//    streamed ONCE per anchor creation (4x, L3-warm) into LDS aihS[4][128]
//    gate-row values; cellB/C add aihS[sel-2][rl] (s==0 slice only).
//  - ws need 124,160 B (proven: ctrl_v11 ran with >=126,976). Fallback to
//    the proven R8-style small-ws kernel kept.

#define NBLK  6
#define PWG   8
#define THR   512
#define TINYF 1.17549435e-38f
#define HTAGB 0xC3B00000u
#define YTAGB 0xE1700000u
#define DONE_MAGIC 0x444f4e45

typedef unsigned long long u64;
struct U2 { uint32_t x, y; };

// ---- v12 ws layout (bytes) ----
#define W_DONE 0u        // int[8]
#define W_PART 64u       // float[12]
#define W_EX   512u      // u64 ex[2][6][8][161]: 128 packed y + 32 tagged h + 1 ytag
#define EXBLK  161
#define W_NEED 124160u

// ---- fallback (proven R8-style) ws layout ----
#define S_READY 0u
#define S_DONE  192u
#define S_PART  224u
#define S_HP    320u
#define S_ACC   24896u
#define FXS     67108864.0f
#define READY_MAGIC 0x52454459

// Threefry-2x32, 20 rounds (Random123 / JAX). Key (k0,k1), counter (c0,c1).
__device__ __forceinline__ U2 tf2x32(uint32_t k0, uint32_t k1,
                                     uint32_t c0, uint32_t c1) {
  uint32_t ks2 = k0 ^ k1 ^ 0x1BD11BDAu;
  uint32_t x0 = c0 + k0, x1 = c1 + k1;
#define TFR(r) { x0 += x1; x1 = (x1 << (r)) | (x1 >> (32 - (r))); x1 ^= x0; }
  TFR(13) TFR(15) TFR(26) TFR(6)   x0 += k1;  x1 += ks2 + 1u;
  TFR(17) TFR(29) TFR(16) TFR(24)  x0 += ks2; x1 += k0 + 2u;
  TFR(13) TFR(15) TFR(26) TFR(6)   x0 += k0;  x1 += k1 + 3u;
  TFR(17) TFR(29) TFR(16) TFR(24)  x0 += k1;  x1 += ks2 + 4u;
  TFR(13) TFR(15) TFR(26) TFR(6)   x0 += ks2; x1 += k0 + 5u;
#undef TFR
  U2 r; r.x = x0; r.y = x1; return r;
}

__device__ __forceinline__ float sigf(float x) {
  return 1.0f / (1.0f + expf(-x));
}
// relaxed agent-scope (LLC-resolved) accessors -- the only sync primitives.
__device__ __forceinline__ void istore(int* p, int v) {
  __hip_atomic_store(p, v, __ATOMIC_RELAXED, __HIP_MEMORY_SCOPE_AGENT);
}
__device__ __forceinline__ int iload(const int* p) {
  return __hip_atomic_load(p, __ATOMIC_RELAXED, __HIP_MEMORY_SCOPE_AGENT);
}
__device__ __forceinline__ void hstore(u64* p, u64 v) {
  __hip_atomic_store(p, v, __ATOMIC_RELAXED, __HIP_MEMORY_SCOPE_AGENT);
}
__device__ __forceinline__ u64 hload(const u64* p) {
  return __hip_atomic_load(p, __ATOMIC_RELAXED, __HIP_MEMORY_SCOPE_AGENT);
}
__device__ __forceinline__ void fstore(float* p, float v) {
  __hip_atomic_store(p, v, __ATOMIC_RELAXED, __HIP_MEMORY_SCOPE_AGENT);
}
__device__ __forceinline__ float fload(const float* p) {
  return __hip_atomic_load(p, __ATOMIC_RELAXED, __HIP_MEMORY_SCOPE_AGENT);
}
__device__ __forceinline__ u64 pollw(const u64* p, uint32_t want) {
  u64 v;
  for (;;) {
    v = hload(p);
    if ((uint32_t)(v >> 32) == want) return v;
    __builtin_amdgcn_s_sleep(1);
  }
}

// =================== R12 kernel ============================================
__global__ __launch_bounds__(THR, 2) void ctrl_v12(
    const float* __restrict__ enc_w,
    const float* __restrict__ wih,
    const float* __restrict__ whh,
    const float* __restrict__ b_ih,
    const float* __restrict__ b_hh,
    const float* __restrict__ w1,
    const float* __restrict__ w2,
    const float* __restrict__ vvec,
    unsigned char* __restrict__ ws,
    float* __restrict__ out) {

  const int b = blockIdx.x & 7;      // XCD swizzle: chain b -> XCD b (if RR)
  const int p = blockIdx.x >> 3;
  if (b >= NBLK) return;
  const int tid = threadIdx.x;

  int*   done = (int*)(ws + W_DONE);
  float* part = (float*)(ws + W_PART);
  u64*   ex   = (u64*)(ws + W_EX);   // [2][6][8][EXBLK]

  // gate GEMV: 128 local rows rl x 4 wave-uniform k-slices s of 64
  const int rl = tid & 127, s = tid >> 7;
  const int grow = (rl >> 5) * 256 + p * 32 + (rl & 31);
  const int k0 = s * 64;
  // y-partial: element rr, col half ks (cols p*32 + ks*16 .. +16)
  const int rr = tid & 255, ks = tid >> 8;
  const int cb = p * 32 + ks * 16;

  __shared__ __align__(16) float gateL[THR];
  __shared__ __align__(16) float hL[256], encL[256], vL[256];
  __shared__ __align__(16) float w2hS[256], aw1S[6][256];
  __shared__ __align__(16) float yL8[8][256];
  __shared__ __align__(16) float aihS[4][128];   // wih@anchor gate-rows
  __shared__ float rowSumL[128], biasS[128], h2S[32];
  __shared__ float logitL[8];

  if (tid < 256) { encL[tid] = enc_w[tid]; vL[tid] = vvec[tid]; }
  if (tid < 128) {
    int r = (tid >> 5) * 256 + p * 32 + (tid & 31);
    biasS[tid] = b_ih[r] + b_hh[r];
  }

  // resident weights: whh rows (64 VGPR) + w1/w2 col slices (32 VGPR)
  float4 whhr[16];
  #pragma unroll
  for (int c = 0; c < 16; ++c)
    whhr[c] = *(const float4*)(whh + grow * 256 + k0 + c * 4);
  float w1c[16], w2c[16];
  #pragma unroll
  for (int j = 0; j < 16; ++j) {
    w1c[j] = w1[rr * 256 + cb + j];
    w2c[j] = w2[rr * 256 + cb + j];
  }
  __syncthreads();

  auto dotHH = [&]() {
    float a = 0.0f;
    #pragma unroll
    for (int c = 0; c < 16; ++c) {
      float4 xv = *(const float4*)(hL + k0 + c * 4);
      float4 w = whhr[c];
      a += w.x * xv.x + w.y * xv.y + w.z * xv.z + w.w * xv.w;
    }
    return a;
  };
  // streamed wih row-slice dot (startup + 4 anchor creations; L3-warm)
  auto dotIHg = [&](const float* x) {
    const float4* wp = (const float4*)(wih + grow * 256 + k0);
    float a = 0.0f;
    #pragma unroll
    for (int c = 0; c < 16; ++c) {
      float4 w = wp[c];
      float4 xv = *(const float4*)(x + k0 + c * 4);
      a += w.x * xv.x + w.y * xv.y + w.z * xv.z + w.w * xv.w;
    }
    return a;
  };

  const float encih = dotIHg(encL);  // per-thread PARTIAL, reduced in gate sum

  float cv = 0.0f;                            // c for element p*32+tid (tid<32)
  U2 bk = tf2x32(0u, 42u, 0u, (uint32_t)b);   // fold_in(key(42), b)
  int k = 1, kc = 0, step = 0;
  float lpAcc = 0.0f, entAcc = 0.0f;

  // cell: gates -> h update -> publish (early tagged h; packed y; y tag) ->
  // poll h. last=true: no exchange, write final c/h.
  auto cell = [&](float gacc, bool isW1, bool last) {
    gateL[tid] = gacc;                       // tid = s*128 + rl
    __syncthreads();
    if (tid < 128) {
      float ssum = 0.0f;
      #pragma unroll
      for (int j = 0; j < 4; ++j) ssum += gateL[j * 128 + tid];
      rowSumL[tid] = ssum + biasS[tid];
    }
    __syncthreads();
    u64* blk = ex + (((size_t)(k & 1) * NBLK + b) * PWG + p) * EXBLK;
    if (tid < 32) {
      float gi = rowSumL[tid],       gf = rowSumL[32 + tid];
      float gg2 = rowSumL[64 + tid], go = rowSumL[96 + tid];
      float c2 = sigf(gf) * cv + sigf(gi) * tanhf(gg2);
      float h2 = sigf(go) * tanhf(c2);
      cv = c2;
      h2S[tid] = h2;
      if (last) {
        if (b == NBLK - 1) { out[62 + p * 32 + tid] = cv; out[318 + p * 32 + tid] = h2; }
      } else {                               // publish tagged h EARLY
        hstore(blk + 128 + tid,
               ((u64)(HTAGB | (uint32_t)k) << 32) | (u64)__float_as_uint(h2));
      }
    }
    __syncthreads();                         // h2S visible
    if (last) return;

    {                                        // own y partial (16 cols)
      const float* wc = isW1 ? w1c : w2c;
      float yp = 0.0f;
      #pragma unroll
      for (int j = 0; j < 16; ++j) yp += wc[j] * h2S[ks * 16 + j];
      gateL[tid] = yp;                       // layout ks*256 + rr
    }
    __syncthreads();
    if (tid < 128) {                         // pack 2 col-summed floats/u64
      float ya = gateL[2 * tid]     + gateL[256 + 2 * tid];
      float yb = gateL[2 * tid + 1] + gateL[256 + 2 * tid + 1];
      hstore(blk + tid,
             ((u64)__float_as_uint(yb) << 32) | (u64)__float_as_uint(ya));
    }
    __syncthreads();                         // vmcnt drain: y at LLC
    if (tid == 0)
      hstore(blk + 160, ((u64)(YTAGB | (uint32_t)k) << 32) | 1u);

    // poll full h (one tagged word per thread, tid<256)
    if (tid < 256) {
      const u64* base = ex + (((size_t)(k & 1) * NBLK + b) * PWG) * EXBLK;
      u64 v = pollw(base + (size_t)(tid >> 5) * EXBLK + 128 + (tid & 31),
                    HTAGB | (uint32_t)k);
      hL[tid] = __uint_as_float((uint32_t)v);
    }
    __syncthreads();
    kc = k;
    ++k;
  };

  // finishY: poll 8 y tags of exchange kc, bulk-read packed y, fixed-order
  // sum -> dest (w2hS or aw1S[aid]). Runs in every wg (identical results).
  auto finishY = [&](int aid, bool isW1) {
    const u64* base = ex + (((size_t)(kc & 1) * NBLK + b) * PWG) * EXBLK;
    if (tid < 8) pollw(base + (size_t)tid * EXBLK + 160, YTAGB | (uint32_t)kc);
    __syncthreads();
    {
      int q = tid >> 6, w0 = (tid & 63) * 2;
      const u64* mb = base + (size_t)q * EXBLK;
      u64 wa = hload(mb + w0), wb = hload(mb + w0 + 1);
      yL8[q][2 * w0 + 0] = __uint_as_float((uint32_t)wa);
      yL8[q][2 * w0 + 1] = __uint_as_float((uint32_t)(wa >> 32));
      yL8[q][2 * w0 + 2] = __uint_as_float((uint32_t)wb);
      yL8[q][2 * w0 + 3] = __uint_as_float((uint32_t)(wb >> 32));
    }
    __syncthreads();
    if (tid < 256) {
      float y = 0.0f;
      #pragma unroll
      for (int q = 0; q < 8; ++q) y += yL8[q][tid];
      if (isW1) aw1S[aid][tid] = y; else w2hS[tid] = y;
    }
    __syncthreads();
  };

  // aih: wih @ hL (anchor h) for this wg's 128 gate rows -> aihS[cid]
  auto makeAih = [&](int cid) {
    float a = dotIHg(hL);
    gateL[tid] = a;
    __syncthreads();
    if (tid < 128) {
      float ssum = 0.0f;
      #pragma unroll
      for (int j = 0; j < 4; ++j) ssum += gateL[j * 128 + tid];
      aihS[cid][tid] = ssum;
    }
    __syncthreads();
  };

  // redundant local sample (identical in every wg); writes arcs if p==0.
  auto sample = [&](int L) -> int {
    int wv = tid >> 6, lane = tid & 63;
    if (wv < L) {
      float a = 0.0f;
      #pragma unroll
      for (int j = 0; j < 4; ++j) {          // stride-64: conflict-free
        int kk = j * 64 + lane;
        a += tanhf(aw1S[wv][kk] + w2hS[kk]) * vL[kk];
      }
      a += __shfl_down(a, 32);
      a += __shfl_down(a, 16);
      a += __shfl_down(a, 8);
      a += __shfl_down(a, 4);
      a += __shfl_down(a, 2);
      a += __shfl_down(a, 1);
      if (lane == 0) logitL[wv] = a;
    }
    __syncthreads();
    int bi = 0;
    {
      // scalar selection, uniform across all threads (cheap: L<=6)
      float lg[6];
      for (int i = 0; i < L; ++i) lg[i] = 1.1f * tanhf(logitL[i] * 0.2f);
      U2 sk = tf2x32(bk.x, bk.y, 0u, (uint32_t)step);
      float best = 0.0f;
      for (int i = 0; i < L; ++i) {
        U2 r2 = tf2x32(sk.x, sk.y, 0u, (uint32_t)i);
        uint32_t bits = r2.x ^ r2.y;
        float u = __uint_as_float((bits >> 9) | 0x3f800000u) - 1.0f;
        u = fmaxf(TINYF, u + TINYF);         // jax uniform(tiny, 1)
        float sg = lg[i] - logf(-logf(u));
        if (i == 0 || sg > best) { best = sg; bi = i; }  // first-max
      }
      if (tid == 0) {
        float mx = lg[0];
        for (int i = 1; i < L; ++i) mx = fmaxf(mx, lg[i]);
        float se = 0.0f;
        for (int i = 0; i < L; ++i) se += expf(lg[i] - mx);
        float lse = logf(se);
        lpAcc += -(lg[bi] - mx - lse);
        float es = 0.0f;
        for (int i = 0; i < L; ++i) {
          float l = lg[i] - mx - lse;
          es += l * expf(l);
        }
        entAcc += -es;
        if (p == 0) out[b * 10 + step] = (float)bi;
      }
    }
    __syncthreads();
    step++;
    return bi;
  };

  // ---- chain ----
  cell(encih, true, false);          // zero-state cell; y = w1 partials
  finishY(0, true);                  // aw1S[0]
  if (tid < 256) aw1S[1][tid] = aw1S[0][tid];
  __syncthreads();

  for (int L = 2; L <= 6; ++L) {
    { float hh = dotHH(); cell(encih + hh, false, false); }      // cellA
    {
      float hh = dotHH();            // overlaps y-tag wait
      finishY(0, false);             // w2hS
      int s1 = sample(L);
      float a = (s1 >= 2 && s == 0) ? aihS[s1 - 2][rl] : 0.0f;
      cell(a + hh, false, false);                                // cellB
    }
    {
      float hh = dotHH();
      finishY(0, false);
      int s2 = sample(L);
      float a = (s2 >= 2 && s == 0) ? aihS[s2 - 2][rl] : 0.0f;
      if (L < 6) {
        cell(a + hh, true, false);                               // cellC
        float hh3 = dotHH();         // overlaps y-tag wait
        finishY(L, true);            // aw1S[L]
        makeAih(L - 2);              // anchor gate rows from hL
        // next cellA gate input: encih + hh3
        cell(encih + hh3, false, false);
        finishY(0, false);
        int s1n = sample(L + 1);
        float an = (s1n >= 2 && s == 0) ? aihS[s1n - 2][rl] : 0.0f;
        float hhn = dotHH();
        cell(an + hhn, false, false);
        finishY(0, false);
        int s2n = sample(L + 1);
        float an2 = (s2n >= 2 && s == 0) ? aihS[s2n - 2][rl] : 0.0f;
        float hhn2 = dotHH();
        // fallthrough handled by loop; emulate by incrementing L
        if (L + 1 < 6) cell(an2 + hhn2, true, false);
        else           cell(an2 + hhn2, false, true);
        if (L + 1 < 6) {
          float hh4 = dotHH();
          finishY(L + 1, true);
          makeAih(L - 1);
          // stash for next loop iteration: emulate cellA of L+2
          // (handled by the loop: skip its cellA via flag)
          gateL[tid] = hh4;          // reuse as stash
        }
        L = L + 1;                   // consumed one extra layer
        if (L < 6) {
          // we already did cellC of layer L; loop continues at L+1 cellA,
          // whose hh is the stashed dotHH of the anchor h
          float hh4 = gateL[tid];
          __syncthreads();
          cell(encih + hh4, false, false);
          finishY(0, false);
          int s1m = sample(L + 1);
          float am = (s1m >= 2 && s == 0) ? aihS[s1m - 2][rl] : 0.0f;
          float hhm = dotHH();
          cell(am + hhm, false, false);
          finishY(0, false);
          int s2m = sample(L + 1);
          float am2 = (s2m >= 2 && s == 0) ? aihS[s2m - 2][rl] : 0.0f;
          float hhm2 = dotHH();
          if (L + 1 < 6) {
            cell(am2 + hhm2, true, false);
            float hh5 = dotHH();
            finishY(L + 1, true);
            makeAih(L);
            gateL[tid] = hh5;
            __syncthreads();
            // continue outer loop at L+2 with stashed hh — but to keep the
            // control flow sane, just unroll the remaining layers directly.
          } else {
            cell(am2 + hhm2, false, true);
          }
          L = L + 1;
        }
      } else {
        cell(a + hh, false, true);                               // last cell
      }
    }
  }

  if (p == 0 && tid == 0) {
    fstore(&part[2 * b], lpAcc);
    fstore(&part[2 * b + 1], entAcc);
    __builtin_amdgcn_s_waitcnt(0);
    istore(&done[b], DONE_MAGIC);
    if (b == NBLK - 1) {
      float lp = 0.0f, en = 0.0f;
      for (int j = 0; j < NBLK; ++j) {
        while (iload(&done[j]) != DONE_MAGIC) __builtin_amdgcn_s_sleep(1);
        lp += fload(&part[2 * j]);
        en += fload(&part[2 * j + 1]);
      }
      out[60] = lp;
      out[61] = en;
    }
  }
}

// =================== fallback (proven R8-style; small ws) ==================
__global__ __launch_bounds__(1024) void ctrl_small(
    const float* __restrict__ enc_w,
    const float* __restrict__ wih,
    const float* __restrict__ whh,
    const float* __restrict__ b_ih,
    const float* __restrict__ b_hh,
    const float* __restrict__ w1,
    const float* __restrict__ w2,
    const float* __restrict__ vvec,
    unsigned char* __restrict__ ws,
    float* __restrict__ out) {

  const int b = blockIdx.x & 7;
  const int p = blockIdx.x >> 3;
  if (b >= NBLK) return;
  const int tid = threadIdx.x;

  int*   ready = (int*)(ws + S_READY);
  int*   done  = (int*)(ws + S_DONE);
  float* part  = (float*)(ws + S_PART);
  u64*   hp    = (u64*)(ws + S_HP);
  int*   acc   = (int*)(ws + S_ACC);

  const int rl = tid >> 3, s = tid & 7;
  const int g = rl >> 5, el = rl & 31;
  const int row = g * 256 + p * 32 + el;
  const int k0 = s * 32;
  const int rr = tid & 255, ks = tid >> 8;

  __shared__ __align__(16) float hL[256], encL[256], vL[256];
  __shared__ __align__(16) float anchL[4][256];
  __shared__ __align__(16) float partL[1024];
  __shared__ __align__(16) float w2hS[256], aw1S[6][256];
  __shared__ float rowSumL[128], biasS[128], h2S[32];
  __shared__ float logitL[8];
  __shared__ int   selL;

  if (tid < 256) { encL[tid] = enc_w[tid]; vL[tid] = vvec[tid]; }
  if (tid < 128) {
    int gg = tid >> 5, ee = tid & 31, r = gg * 256 + p * 32 + ee;
    biasS[tid] = b_ih[r] + b_hh[r];
  }

  float4 wihr[8], whhr[8];
  #pragma unroll
  for (int c = 0; c < 8; ++c) {
    int cc = (c + s) & 7;
    wihr[c] = *(const float4*)(wih + row * 256 + k0 + cc * 4);
    whhr[c] = *(const float4*)(whh + row * 256 + k0 + cc * 4);
  }
  float w1c[8], w2c[8];
  #pragma unroll
  for (int j = 0; j < 8; ++j) {
    w1c[j] = w1[rr * 256 + p * 32 + ks * 8 + j];
    w2c[j] = w2[rr * 256 + p * 32 + ks * 8 + j];
  }

  if (tid < 32) istore(&acc[1 * (NBLK * 256) + b * 256 + p * 32 + tid], 0);
  __syncthreads();
  if (tid == 0) istore(&ready[b * 8 + p], READY_MAGIC);
  if (tid < 8) {
    while (iload(&ready[b * 8 + tid]) != READY_MAGIC)
      __builtin_amdgcn_s_sleep(1);
  }
  __syncthreads();

  auto dotIH = [&](const float* x) {
    float a = 0.0f;
    #pragma unroll
    for (int c = 0; c < 8; ++c) {
      int cc = (c + s) & 7;
      float4 xv = *(const float4*)(x + k0 + cc * 4);
      float4 w = wihr[c];
      a += w.x * xv.x + w.y * xv.y + w.z * xv.z + w.w * xv.w;
    }
    return a;
  };
  auto dotHH = [&]() {
    float a = 0.0f;
    #pragma unroll
    for (int c = 0; c < 8; ++c) {
      int cc = (c + s) & 7;
      float4 xv = *(const float4*)(hL + k0 + cc * 4);
      float4 w = whhr[c];
      a += w.x * xv.x + w.y * xv.y + w.z * xv.z + w.w * xv.w;
    }
    return a;
  };

  const float encih = dotIH(encL);
  float cv = 0.0f;
  U2 bk = tf2x32(0u, 42u, 0u, (uint32_t)b);
  int k = 1, step = 0;
  float lpAcc = 0.0f, entAcc = 0.0f;

  auto cell = [&](float gacc, int mode, int aid, int cid) {
    partL[tid] = gacc;
    __syncthreads();
    if (tid < 128) {
      float ssum = 0.0f;
      #pragma unroll
      for (int j = 0; j < 8; ++j) ssum += partL[tid * 8 + j];
      rowSumL[tid] = ssum + biasS[tid];
    }
    __syncthreads();
    if (tid < 32) {
      float gi = rowSumL[tid],       gf = rowSumL[32 + tid];
      float gg2 = rowSumL[64 + tid], go = rowSumL[96 + tid];
      float c2 = sigf(gf) * cv + sigf(gi) * tanhf(gg2);
      float h2 = sigf(go) * tanhf(c2);
      cv = c2;
      h2S[tid] = h2;
      if (mode == 2 && b == NBLK - 1) {
        out[62 + p * 32 + tid] = cv;
        out[318 + p * 32 + tid] = h2;
      }
    }
    __syncthreads();
    if (mode == 2) return;
    {
      const float* wc = (mode == 1) ? w1c : w2c;
      float yp = 0.0f;
      #pragma unroll
      for (int j = 0; j < 8; ++j) yp += wc[j] * h2S[ks * 8 + j];
      atomicAdd(&acc[(k % 3) * (NBLK * 256) + b * 256 + rr],
                __float2int_rn(yp * FXS));
      if (tid < 32)
        istore(&acc[((k + 1) % 3) * (NBLK * 256) + b * 256 + p * 32 + tid], 0);
    }
    __syncthreads();
    if (tid < 32) {
      u64 pk = ((u64)(uint32_t)k << 32) | (u64)__float_as_uint(h2S[tid]);
      hstore(&hp[(k & 1) * (NBLK * 256) + b * 256 + p * 32 + tid], pk);
    }
    if (tid < 256) {
      u64 v;
      const u64* src = &hp[(k & 1) * (NBLK * 256) + b * 256 + tid];
      while ((int)(hload(src) >> 32) != k) __builtin_amdgcn_s_sleep(1);
      v = hload(src);
      float hv = __uint_as_float((uint32_t)v);
      hL[tid] = hv;
      if (mode == 1 && cid >= 0) anchL[cid][tid] = hv;
    }
    __syncthreads();
    if (tid < 256) {
      int iv = iload(&acc[(k % 3) * (NBLK * 256) + b * 256 + tid]);
      float f = (float)((double)iv * (1.0 / 67108864.0));
      if (mode == 1) aw1S[aid][tid] = f; else w2hS[tid] = f;
    }
    __syncthreads();
    ++k;
  };

  auto sample = [&](int L) -> int {
    int wv = tid >> 6, lane = tid & 63;
    if (wv < L) {
      float a = 0.0f;
      #pragma unroll
      for (int j = 0; j < 4; ++j) {
        int kk = lane * 4 + j;
        a += tanhf(aw1S[wv][kk] + w2hS[kk]) * vL[kk];
      }
      a += __shfl_down(a, 32);
      a += __shfl_down(a, 16);
      a += __shfl_down(a, 8);
      a += __shfl_down(a, 4);
      a += __shfl_down(a, 2);
      a += __shfl_down(a, 1);
      if (lane == 0) logitL[wv] = a;
    }
    __syncthreads();
    if (tid < 64) {
      float lg = 0.0f, sgum = -1e30f;
      if (tid < L) {
        lg = 1.1f * tanhf(logitL[tid] * 0.2f);
        U2 sk = tf2x32(bk.x, bk.y, 0u, (uint32_t)step);
        U2 r2 = tf2x32(sk.x, sk.y, 0u, (uint32_t)tid);
        uint32_t bits = r2.x ^ r2.y;
        float u = __uint_as_float((bits >> 9) | 0x3f800000u) - 1.0f;
        u = fmaxf(TINYF, u + TINYF);
        sgum = lg - logf(-logf(u));
      }
      int bi = 0;
      float best = __shfl(sgum, 0, 64);
      for (int j = 1; j < L; ++j) {
        float sj = __shfl(sgum, j, 64);
        if (sj > best) { best = sj; bi = j; }
      }
      float mx = __shfl(lg, 0, 64);
      for (int j = 1; j < L; ++j) mx = fmaxf(mx, __shfl(lg, j, 64));
      float se = 0.0f;
      for (int j = 0; j < L; ++j) se += expf(__shfl(lg, j, 64) - mx);
      float lse = logf(se);
      float lgbi = __shfl(lg, bi, 64);
      float es = 0.0f;
      for (int j = 0; j < L; ++j) {
        float l = __shfl(lg, j, 64) - mx - lse;
        es += l * expf(l);
      }
      if (tid == 0) {
        lpAcc += -(lgbi - mx - lse);
        entAcc += -es;
        selL = bi;
        if (p == 0) out[b * 10 + step] = (float)bi;
      }
    }
    __syncthreads();
    step++;
    return selL;
  };

  cell(encih, 1, 0, -1);
  if (tid < 256) aw1S[1][tid] = aw1S[0][tid];
  __syncthreads();
  for (int L = 2; L <= 6; ++L) {
    cell(encih + dotHH(), 0, 0, -1);
    int s1v = sample(L);
    {
      float a = (s1v >= 2) ? dotIH(&anchL[s1v - 2][0]) : 0.0f;
      cell(a + dotHH(), 0, 0, -1);
    }
    int s2v = sample(L);
    {
      float a = (s2v >= 2) ? dotIH(&anchL[s2v - 2][0]) : 0.0f;
      if (L < 6) cell(a + dotHH(), 1, L, L - 2);
      else       cell(a + dotHH(), 2, 0, -1);
    }
  }
  if (p == 0 && tid == 0) {
    fstore(&part[2 * b], lpAcc);
    fstore(&part[2 * b + 1], entAcc);
    __builtin_amdgcn_s_waitcnt(0);
    istore(&done[b], DONE_MAGIC);
    if (b == NBLK - 1) {
      float lp = 0.0f, en = 0.0f;
      for (int j = 0; j < NBLK; ++j) {
        while (iload(&done[j]) != DONE_MAGIC) __builtin_amdgcn_s_sleep(1);
        lp += fload(&part[2 * j]);
        en += fload(&part[2 * j + 1]);
      }
      out[60] = lp;
      out[61] = en;
    }
  }
}

extern "C" void kernel_launch(void* const* d_in, const int* in_sizes, int n_in,
                              void* d_out, int out_size, void* d_ws, size_t ws_size,
                              hipStream_t stream) {
  const float* enc = (const float*)d_in[0];
  const float* wih = (const float*)d_in[1];
  const float* whh = (const float*)d_in[2];
  const float* bih = (const float*)d_in[3];
  const float* bhh = (const float*)d_in[4];
  const float* w1  = (const float*)d_in[5];
  const float* w2  = (const float*)d_in[6];
  const float* v   = (const float*)d_in[7];
  unsigned char* ws = (unsigned char*)d_ws;
  float* out = (float*)d_out;

  if (ws_size >= W_NEED) {
    ctrl_v12<<<dim3(64), dim3(THR), 0, stream>>>(
        enc, wih, whh, bih, bhh, w1, w2, v, ws, out);
  } else {
    ctrl_small<<<dim3(64), dim3(1024), 0, stream>>>(
        enc, wih, whh, bih, bhh, w1, w2, v, ws, out);
  }
}

// Round 13
// 162.822 us; speedup vs baseline: 1.0662x; 1.0662x over previous
//
#include <hip/hip_runtime.h>
#include <stdint.h>

// ENAS LSTM controller. R13 = R11 skeleton (centralized sampling; peers poll
// 256 tagged h words + ONE reusable idx word) + R12 weight layout (whh-only
// VGPR residency, aihS LDS anchor precompute -> no spill), straight-line
// control flow (R12's nested unroll was the regression).
//  - Per cell: publish 32 tagged h words FIRST, then 256 tagged y words
//    (no drain-before-tag); peers poll h only; wg0 polls y (4 words/thread),
//    samples, stores idx word (tag=step; reuse safe: wg0 cannot reach sample
//    s+1 before all peers consumed idx s -- it must observe their next h
//    first). Exchange region byte-identical to the PROVEN V10 footprint
//    (EX @512, 288 u64/wg, total 221,696 B).
//  - makeAih streams wih once per anchor (L2-warm) into aihS[4][128];
//    cellB/C add aihS[sel-2][rl] on the s==0 slice only.
// Fallback to the proven R8-style small-ws kernel if ws is tiny.

#define NBLK  6
#define PWG   8
#define THR   512
#define TINYF 1.17549435e-38f
#define HTAGB 0xC3B00000u
#define YTAGB 0xE1700000u
#define ITAGB 0xA5D00000u
#define DONE_MAGIC 0x444f4e45

typedef unsigned long long u64;
struct U2 { uint32_t x, y; };

// ---- v13 ws layout (bytes); identical total to proven V10 (221,696) ----
#define W_DONE 0u        // int[8]     (32B)
#define W_PART 32u       // float[12]  (48B)
#define W_IDX  96u       // u64[8]     (64B) one reusable idx word per chain
#define W_EX   512u      // u64 ex[2][6][8][288] = 221,184
#define EXBLK  288
#define W_NEED 221696u

// ---- fallback (proven R8-style) ws layout ----
#define S_READY 0u
#define S_DONE  192u
#define S_PART  224u
#define S_HP    320u
#define S_ACC   24896u
#define FXS     67108864.0f
#define READY_MAGIC 0x52454459

// Threefry-2x32, 20 rounds (Random123 / JAX). Key (k0,k1), counter (c0,c1).
__device__ __forceinline__ U2 tf2x32(uint32_t k0, uint32_t k1,
                                     uint32_t c0, uint32_t c1) {
  uint32_t ks2 = k0 ^ k1 ^ 0x1BD11BDAu;
  uint32_t x0 = c0 + k0, x1 = c1 + k1;
#define TFR(r) { x0 += x1; x1 = (x1 << (r)) | (x1 >> (32 - (r))); x1 ^= x0; }
  TFR(13) TFR(15) TFR(26) TFR(6)   x0 += k1;  x1 += ks2 + 1u;
  TFR(17) TFR(29) TFR(16) TFR(24)  x0 += ks2; x1 += k0 + 2u;
  TFR(13) TFR(15) TFR(26) TFR(6)   x0 += k0;  x1 += k1 + 3u;
  TFR(17) TFR(29) TFR(16) TFR(24)  x0 += k1;  x1 += ks2 + 4u;
  TFR(13) TFR(15) TFR(26) TFR(6)   x0 += ks2; x1 += k0 + 5u;
#undef TFR
  U2 r; r.x = x0; r.y = x1; return r;
}

__device__ __forceinline__ float sigf(float x) {
  return 1.0f / (1.0f + expf(-x));
}
// relaxed agent-scope (LLC-resolved) accessors -- the only sync primitives.
__device__ __forceinline__ void istore(int* p, int v) {
  __hip_atomic_store(p, v, __ATOMIC_RELAXED, __HIP_MEMORY_SCOPE_AGENT);
}
__device__ __forceinline__ int iload(const int* p) {
  return __hip_atomic_load(p, __ATOMIC_RELAXED, __HIP_MEMORY_SCOPE_AGENT);
}
__device__ __forceinline__ void hstore(u64* p, u64 v) {
  __hip_atomic_store(p, v, __ATOMIC_RELAXED, __HIP_MEMORY_SCOPE_AGENT);
}
__device__ __forceinline__ u64 hload(const u64* p) {
  return __hip_atomic_load(p, __ATOMIC_RELAXED, __HIP_MEMORY_SCOPE_AGENT);
}
__device__ __forceinline__ void fstore(float* p, float v) {
  __hip_atomic_store(p, v, __ATOMIC_RELAXED, __HIP_MEMORY_SCOPE_AGENT);
}
__device__ __forceinline__ float fload(const float* p) {
  return __hip_atomic_load(p, __ATOMIC_RELAXED, __HIP_MEMORY_SCOPE_AGENT);
}
__device__ __forceinline__ u64 pollw(const u64* p, uint32_t want) {
  u64 v;
  for (;;) {
    v = hload(p);
    if ((uint32_t)(v >> 32) == want) return v;
    __builtin_amdgcn_s_sleep(1);
  }
}

// =================== R13 kernel ============================================
__global__ __launch_bounds__(THR, 2) void ctrl_v13(
    const float* __restrict__ enc_w,
    const float* __restrict__ wih,
    const float* __restrict__ whh,
    const float* __restrict__ b_ih,
    const float* __restrict__ b_hh,
    const float* __restrict__ w1,
    const float* __restrict__ w2,
    const float* __restrict__ vvec,
    unsigned char* __restrict__ ws,
    float* __restrict__ out) {

  const int b = blockIdx.x & 7;      // XCD swizzle: chain b -> XCD b (if RR)
  const int p = blockIdx.x >> 3;
  if (b >= NBLK) return;
  const int tid = threadIdx.x;

  int*   done = (int*)(ws + W_DONE);
  float* part = (float*)(ws + W_PART);
  u64*   idxw = (u64*)(ws + W_IDX);
  u64*   ex   = (u64*)(ws + W_EX);   // [2][6][8][EXBLK]

  // gate GEMV: 128 local rows rl x 4 wave-uniform k-slices s of 64
  const int rl = tid & 127, s = tid >> 7;
  const int grow = (rl >> 5) * 256 + p * 32 + (rl & 31);
  const int k0 = s * 64;
  // y-partial: element rr, col half ks (cols p*32 + ks*16 .. +16)
  const int rr = tid & 255, ks = tid >> 8;
  const int cb = p * 32 + ks * 16;

  __shared__ __align__(16) float gateL[THR];
  __shared__ __align__(16) float hL[256], encL[256], vL[256];
  __shared__ __align__(16) float w2hS[256], aw1S[6][256];
  __shared__ __align__(16) float aihS[4][128];   // wih@anchor gate-rows
  __shared__ float rowSumL[128], biasS[128], h2S[32];
  __shared__ float logitL[8];
  __shared__ int   selL;

  if (tid < 256) { encL[tid] = enc_w[tid]; vL[tid] = vvec[tid]; }
  if (tid < 128) {
    int r = (tid >> 5) * 256 + p * 32 + (tid & 31);
    biasS[tid] = b_ih[r] + b_hh[r];
  }

  // resident weights: whh rows (64 VGPR) + w1/w2 col slices (32 VGPR)
  float4 whhr[16];
  #pragma unroll
  for (int c = 0; c < 16; ++c)
    whhr[c] = *(const float4*)(whh + grow * 256 + k0 + c * 4);
  float w1c[16], w2c[16];
  #pragma unroll
  for (int j = 0; j < 16; ++j) {
    w1c[j] = w1[rr * 256 + cb + j];
    w2c[j] = w2[rr * 256 + cb + j];
  }
  __syncthreads();

  auto dotHH = [&]() {
    float a = 0.0f;
    #pragma unroll
    for (int c = 0; c < 16; ++c) {
      float4 xv = *(const float4*)(hL + k0 + c * 4);
      float4 w = whhr[c];
      a += w.x * xv.x + w.y * xv.y + w.z * xv.z + w.w * xv.w;
    }
    return a;
  };
  // streamed wih row-slice dot (startup + 4 anchor creations; L2-warm)
  auto dotIHg = [&](const float* x) {
    const float4* wp = (const float4*)(wih + grow * 256 + k0);
    float a = 0.0f;
    #pragma unroll
    for (int c = 0; c < 16; ++c) {
      float4 w = wp[c];
      float4 xv = *(const float4*)(x + k0 + c * 4);
      a += w.x * xv.x + w.y * xv.y + w.z * xv.z + w.w * xv.w;
    }
    return a;
  };

  const float encihP = dotIHg(encL);  // per-thread partial, reduced in gates

  float cv = 0.0f;                            // c for element p*32+tid (tid<32)
  U2 bk = tf2x32(0u, 42u, 0u, (uint32_t)b);   // fold_in(key(42), b)
  int k = 1, step = 0;
  float lpAcc = 0.0f, entAcc = 0.0f;

  // cell: gates -> h,c -> publish tagged h (first) + tagged y -> poll h.
  auto cell = [&](float gacc, bool yIsW1, bool last) {
    gateL[tid] = gacc;                       // tid = s*128 + rl
    __syncthreads();
    if (tid < 128) {
      float ssum = 0.0f;
      #pragma unroll
      for (int j = 0; j < 4; ++j) ssum += gateL[j * 128 + tid];
      rowSumL[tid] = ssum + biasS[tid];
    }
    __syncthreads();
    u64* blk = ex + (((size_t)(k & 1) * NBLK + b) * PWG + p) * EXBLK;
    if (tid < 32) {
      float gi = rowSumL[tid],       gf = rowSumL[32 + tid];
      float gg2 = rowSumL[64 + tid], go = rowSumL[96 + tid];
      float c2 = sigf(gf) * cv + sigf(gi) * tanhf(gg2);
      float h2 = sigf(go) * tanhf(c2);
      cv = c2;
      h2S[tid] = h2;
      if (last) {
        if (b == NBLK - 1) { out[62 + p * 32 + tid] = cv; out[318 + p * 32 + tid] = h2; }
      } else {                               // tagged h, published FIRST
        hstore(blk + 256 + tid,
               ((u64)(HTAGB | (uint32_t)k) << 32) | (u64)__float_as_uint(h2));
      }
    }
    __syncthreads();                         // h2S visible
    if (last) return;

    {                                        // own y partial (16 cols)
      const float* wc = yIsW1 ? w1c : w2c;
      float yp = 0.0f;
      #pragma unroll
      for (int j = 0; j < 16; ++j) yp += wc[j] * h2S[ks * 16 + j];
      gateL[tid] = yp;                       // layout ks*256 + rr
    }
    __syncthreads();
    if (tid < 256) {                         // tagged y (no drain needed)
      float yo = gateL[tid] + gateL[256 + tid];
      hstore(blk + tid,
             ((u64)(YTAGB | (uint32_t)k) << 32) | (u64)__float_as_uint(yo));
    }
    // poll peers' h (the only thing peers need)
    if (tid < 256) {
      const u64* base = ex + (((size_t)(k & 1) * NBLK + b) * PWG) * EXBLK;
      u64 v = pollw(base + (size_t)(tid >> 5) * EXBLK + 256 + (tid & 31),
                    HTAGB | (uint32_t)k);
      hL[tid] = __uint_as_float((uint32_t)v);
    }
    __syncthreads();
    ++k;
  };

  // wg0 only: gather y of exchange k-1 into dest (w2hS or aw1S[aid])
  auto gatherY = [&](float* dest) {
    const uint32_t tg = YTAGB | (uint32_t)(k - 1);
    const u64* base = ex + (((size_t)((k - 1) & 1) * NBLK + b) * PWG) * EXBLK;
    float acc = 0.0f;
    int e = tid & 255, q0 = tid >> 8;
    #pragma unroll
    for (int qq = 0; qq < 4; ++qq) {
      int q = q0 + 2 * qq;
      u64 v = pollw(base + (size_t)q * EXBLK + e, tg);
      acc += __uint_as_float((uint32_t)v);
    }
    gateL[tid] = acc;
    __syncthreads();
    if (tid < 256) dest[tid] = gateL[tid] + gateL[256 + tid];
    __syncthreads();
  };

  // aih: wih @ hL (anchor h) for this wg's 128 gate rows -> aihS[cid]
  auto makeAih = [&](int cid) {
    float a = dotIHg(hL);
    gateL[tid] = a;
    __syncthreads();
    if (tid < 128) {
      float ssum = 0.0f;
      #pragma unroll
      for (int j = 0; j < 4; ++j) ssum += gateL[j * 128 + tid];
      aihS[cid][tid] = ssum;
    }
    __syncthreads();
  };

  // wg0: compute logits from aw1S/w2hS, sample, store idx word. uniform ret.
  auto sampleStep = [&](int L) -> int {
    int wv = tid >> 6, lane = tid & 63;
    if (wv < L) {
      float a = 0.0f;
      #pragma unroll
      for (int j = 0; j < 4; ++j) {          // stride-64: conflict-free
        int kk = j * 64 + lane;
        a += tanhf(aw1S[wv][kk] + w2hS[kk]) * vL[kk];
      }
      a += __shfl_down(a, 32);
      a += __shfl_down(a, 16);
      a += __shfl_down(a, 8);
      a += __shfl_down(a, 4);
      a += __shfl_down(a, 2);
      a += __shfl_down(a, 1);
      if (lane == 0) logitL[wv] = a;
    }
    __syncthreads();
    if (tid < 64) {                          // wave 0: lane-parallel selection
      float lg = 0.0f, sgum = -1e30f;
      if (tid < L) {
        lg = 1.1f * tanhf(logitL[tid] * 0.2f);
        U2 sk = tf2x32(bk.x, bk.y, 0u, (uint32_t)step);
        U2 r2 = tf2x32(sk.x, sk.y, 0u, (uint32_t)tid);
        uint32_t bits = r2.x ^ r2.y;
        float u = __uint_as_float((bits >> 9) | 0x3f800000u) - 1.0f;
        u = fmaxf(TINYF, u + TINYF);         // jax uniform(tiny, 1)
        sgum = lg - logf(-logf(u));
      }
      int bi = 0;
      float best = __shfl(sgum, 0, 64);
      for (int j = 1; j < L; ++j) {
        float sj = __shfl(sgum, j, 64);
        if (sj > best) { best = sj; bi = j; }   // first-max = jnp.argmax
      }
      float mx = __shfl(lg, 0, 64);
      for (int j = 1; j < L; ++j) mx = fmaxf(mx, __shfl(lg, j, 64));
      float se = 0.0f;
      for (int j = 0; j < L; ++j) se += expf(__shfl(lg, j, 64) - mx);
      float lse = logf(se);
      float lgbi = __shfl(lg, bi, 64);
      float es = 0.0f;
      for (int j = 0; j < L; ++j) {
        float l = __shfl(lg, j, 64) - mx - lse;
        es += l * expf(l);
      }
      if (tid == 0) {
        lpAcc += -(lgbi - mx - lse);
        entAcc += -es;
        selL = bi;
        out[b * 10 + step] = (float)bi;
        hstore(&idxw[b],
               ((u64)(ITAGB | (uint32_t)step) << 32) | (u64)(uint32_t)bi);
      }
    }
    __syncthreads();
    step++;
    return selL;
  };

  auto pollIdx = [&]() -> int {              // peers: one tagged word
    if (tid == 0) {
      u64 v = pollw(&idxw[b], ITAGB | (uint32_t)step);
      selL = (int)(uint32_t)v;
    }
    __syncthreads();
    step++;
    return selL;
  };

  // ---- chain (straight-line) ----
  cell(encihP, true, false);                 // k=1: zero-state cell, y=w1
  if (p == 0) {
    gatherY(&aw1S[0][0]);
    if (tid < 256) aw1S[1][tid] = aw1S[0][tid];
    __syncthreads();
  }

  for (int L = 2; L <= 6; ++L) {
    // cellA (input enc)
    { float hh = dotHH(); cell(encihP + hh, false, false); }
    // sample 1 -> cellB
    {
      int s1; float hh;
      if (p == 0) { gatherY(w2hS); s1 = sampleStep(L); hh = dotHH(); }
      else        { hh = dotHH(); s1 = pollIdx(); }
      float aacc = (s1 >= 2 && s == 0) ? aihS[s1 - 2][rl] : 0.0f;
      cell(aacc + hh, false, false);
    }
    // sample 2 -> cellC (anchor for L<6; final for L==6)
    {
      int s2; float hh;
      if (p == 0) { gatherY(w2hS); s2 = sampleStep(L); hh = dotHH(); }
      else        { hh = dotHH(); s2 = pollIdx(); }
      float aacc = (s2 >= 2 && s == 0) ? aihS[s2 - 2][rl] : 0.0f;
      if (L < 6) {
        cell(aacc + hh, true, false);        // y = w1 partials
        if (p == 0) gatherY(&aw1S[L][0]);
        makeAih(L - 2);                      // hL == anchor h here
      } else {
        cell(aacc + hh, false, true);        // last cell
      }
    }
  }

  if (p == 0 && tid == 0) {
    fstore(&part[2 * b], lpAcc);
    fstore(&part[2 * b + 1], entAcc);
    __builtin_amdgcn_s_waitcnt(0);
    istore(&done[b], DONE_MAGIC);
    if (b == NBLK - 1) {
      float lp = 0.0f, en = 0.0f;
      for (int j = 0; j < NBLK; ++j) {
        while (iload(&done[j]) != DONE_MAGIC) __builtin_amdgcn_s_sleep(1);
        lp += fload(&part[2 * j]);
        en += fload(&part[2 * j + 1]);
      }
      out[60] = lp;
      out[61] = en;
    }
  }
}

// =================== fallback (proven R8-style; small ws) ==================
__global__ __launch_bounds__(1024) void ctrl_small(
    const float* __restrict__ enc_w,
    const float* __restrict__ wih,
    const float* __restrict__ whh,
    const float* __restrict__ b_ih,
    const float* __restrict__ b_hh,
    const float* __restrict__ w1,
    const float* __restrict__ w2,
    const float* __restrict__ vvec,
    unsigned char* __restrict__ ws,
    float* __restrict__ out) {

  const int b = blockIdx.x & 7;
  const int p = blockIdx.x >> 3;
  if (b >= NBLK) return;
  const int tid = threadIdx.x;

  int*   ready = (int*)(ws + S_READY);
  int*   done  = (int*)(ws + S_DONE);
  float* part  = (float*)(ws + S_PART);
  u64*   hp    = (u64*)(ws + S_HP);
  int*   acc   = (int*)(ws + S_ACC);

  const int rl = tid >> 3, s = tid & 7;
  const int g = rl >> 5, el = rl & 31;
  const int row = g * 256 + p * 32 + el;
  const int k0 = s * 32;
  const int rr = tid & 255, ks = tid >> 8;

  __shared__ __align__(16) float hL[256], encL[256], vL[256];
  __shared__ __align__(16) float anchL[4][256];
  __shared__ __align__(16) float partL[1024];
  __shared__ __align__(16) float w2hS[256], aw1S[6][256];
  __shared__ float rowSumL[128], biasS[128], h2S[32];
  __shared__ float logitL[8];
  __shared__ int   selL;

  if (tid < 256) { encL[tid] = enc_w[tid]; vL[tid] = vvec[tid]; }
  if (tid < 128) {
    int gg = tid >> 5, ee = tid & 31, r = gg * 256 + p * 32 + ee;
    biasS[tid] = b_ih[r] + b_hh[r];
  }

  float4 wihr[8], whhr[8];
  #pragma unroll
  for (int c = 0; c < 8; ++c) {
    int cc = (c + s) & 7;
    wihr[c] = *(const float4*)(wih + row * 256 + k0 + cc * 4);
    whhr[c] = *(const float4*)(whh + row * 256 + k0 + cc * 4);
  }
  float w1c[8], w2c[8];
  #pragma unroll
  for (int j = 0; j < 8; ++j) {
    w1c[j] = w1[rr * 256 + p * 32 + ks * 8 + j];
    w2c[j] = w2[rr * 256 + p * 32 + ks * 8 + j];
  }

  if (tid < 32) istore(&acc[1 * (NBLK * 256) + b * 256 + p * 32 + tid], 0);
  __syncthreads();
  if (tid == 0) istore(&ready[b * 8 + p], READY_MAGIC);
  if (tid < 8) {
    while (iload(&ready[b * 8 + tid]) != READY_MAGIC)
      __builtin_amdgcn_s_sleep(1);
  }
  __syncthreads();

  auto dotIH = [&](const float* x) {
    float a = 0.0f;
    #pragma unroll
    for (int c = 0; c < 8; ++c) {
      int cc = (c + s) & 7;
      float4 xv = *(const float4*)(x + k0 + cc * 4);
      float4 w = wihr[c];
      a += w.x * xv.x + w.y * xv.y + w.z * xv.z + w.w * xv.w;
    }
    return a;
  };
  auto dotHH = [&]() {
    float a = 0.0f;
    #pragma unroll
    for (int c = 0; c < 8; ++c) {
      int cc = (c + s) & 7;
      float4 xv = *(const float4*)(hL + k0 + cc * 4);
      float4 w = whhr[c];
      a += w.x * xv.x + w.y * xv.y + w.z * xv.z + w.w * xv.w;
    }
    return a;
  };

  const float encih = dotIH(encL);
  float cv = 0.0f;
  U2 bk = tf2x32(0u, 42u, 0u, (uint32_t)b);
  int k = 1, step = 0;
  float lpAcc = 0.0f, entAcc = 0.0f;

  auto cell = [&](float gacc, int mode, int aid, int cid) {
    partL[tid] = gacc;
    __syncthreads();
    if (tid < 128) {
      float ssum = 0.0f;
      #pragma unroll
      for (int j = 0; j < 8; ++j) ssum += partL[tid * 8 + j];
      rowSumL[tid] = ssum + biasS[tid];
    }
    __syncthreads();
    if (tid < 32) {
      float gi = rowSumL[tid],       gf = rowSumL[32 + tid];
      float gg2 = rowSumL[64 + tid], go = rowSumL[96 + tid];
      float c2 = sigf(gf) * cv + sigf(gi) * tanhf(gg2);
      float h2 = sigf(go) * tanhf(c2);
      cv = c2;
      h2S[tid] = h2;
      if (mode == 2 && b == NBLK - 1) {
        out[62 + p * 32 + tid] = cv;
        out[318 + p * 32 + tid] = h2;
      }
    }
    __syncthreads();
    if (mode == 2) return;
    {
      const float* wc = (mode == 1) ? w1c : w2c;
      float yp = 0.0f;
      #pragma unroll
      for (int j = 0; j < 8; ++j) yp += wc[j] * h2S[ks * 8 + j];
      atomicAdd(&acc[(k % 3) * (NBLK * 256) + b * 256 + rr],
                __float2int_rn(yp * FXS));
      if (tid < 32)
        istore(&acc[((k + 1) % 3) * (NBLK * 256) + b * 256 + p * 32 + tid], 0);
    }
    __syncthreads();
    if (tid < 32) {
      u64 pk = ((u64)(uint32_t)k << 32) | (u64)__float_as_uint(h2S[tid]);
      hstore(&hp[(k & 1) * (NBLK * 256) + b * 256 + p * 32 + tid], pk);
    }
    if (tid < 256) {
      u64 v;
      const u64* src = &hp[(k & 1) * (NBLK * 256) + b * 256 + tid];
      while ((int)(hload(src) >> 32) != k) __builtin_amdgcn_s_sleep(1);
      v = hload(src);
      float hv = __uint_as_float((uint32_t)v);
      hL[tid] = hv;
      if (mode == 1 && cid >= 0) anchL[cid][tid] = hv;
    }
    __syncthreads();
    if (tid < 256) {
      int iv = iload(&acc[(k % 3) * (NBLK * 256) + b * 256 + tid]);
      float f = (float)((double)iv * (1.0 / 67108864.0));
      if (mode == 1) aw1S[aid][tid] = f; else w2hS[tid] = f;
    }
    __syncthreads();
    ++k;
  };

  auto sample = [&](int L) -> int {
    int wv = tid >> 6, lane = tid & 63;
    if (wv < L) {
      float a = 0.0f;
      #pragma unroll
      for (int j = 0; j < 4; ++j) {
        int kk = lane * 4 + j;
        a += tanhf(aw1S[wv][kk] + w2hS[kk]) * vL[kk];
      }
      a += __shfl_down(a, 32);
      a += __shfl_down(a, 16);
      a += __shfl_down(a, 8);
      a += __shfl_down(a, 4);
      a += __shfl_down(a, 2);
      a += __shfl_down(a, 1);
      if (lane == 0) logitL[wv] = a;
    }
    __syncthreads();
    if (tid < 64) {
      float lg = 0.0f, sgum = -1e30f;
      if (tid < L) {
        lg = 1.1f * tanhf(logitL[tid] * 0.2f);
        U2 sk = tf2x32(bk.x, bk.y, 0u, (uint32_t)step);
        U2 r2 = tf2x32(sk.x, sk.y, 0u, (uint32_t)tid);
        uint32_t bits = r2.x ^ r2.y;
        float u = __uint_as_float((bits >> 9) | 0x3f800000u) - 1.0f;
        u = fmaxf(TINYF, u + TINYF);
        sgum = lg - logf(-logf(u));
      }
      int bi = 0;
      float best = __shfl(sgum, 0, 64);
      for (int j = 1; j < L; ++j) {
        float sj = __shfl(sgum, j, 64);
        if (sj > best) { best = sj; bi = j; }
      }
      float mx = __shfl(lg, 0, 64);
      for (int j = 1; j < L; ++j) mx = fmaxf(mx, __shfl(lg, j, 64));
      float se = 0.0f;
      for (int j = 0; j < L; ++j) se += expf(__shfl(lg, j, 64) - mx);
      float lse = logf(se);
      float lgbi = __shfl(lg, bi, 64);
      float es = 0.0f;
      for (int j = 0; j < L; ++j) {
        float l = __shfl(lg, j, 64) - mx - lse;
        es += l * expf(l);
      }
      if (tid == 0) {
        lpAcc += -(lgbi - mx - lse);
        entAcc += -es;
        selL = bi;
        if (p == 0) out[b * 10 + step] = (float)bi;
      }
    }
    __syncthreads();
    step++;
    return selL;
  };

  cell(encih, 1, 0, -1);
  if (tid < 256) aw1S[1][tid] = aw1S[0][tid];
  __syncthreads();
  for (int L = 2; L <= 6; ++L) {
    cell(encih + dotHH(), 0, 0, -1);
    int s1v = sample(L);
    {
      float a = (s1v >= 2) ? dotIH(&anchL[s1v - 2][0]) : 0.0f;
      cell(a + dotHH(), 0, 0, -1);
    }
    int s2v = sample(L);
    {
      float a = (s2v >= 2) ? dotIH(&anchL[s2v - 2][0]) : 0.0f;
      if (L < 6) cell(a + dotHH(), 1, L, L - 2);
      else       cell(a + dotHH(), 2, 0, -1);
    }
  }
  if (p == 0 && tid == 0) {
    fstore(&part[2 * b], lpAcc);
    fstore(&part[2 * b + 1], entAcc);
    __builtin_amdgcn_s_waitcnt(0);
    istore(&done[b], DONE_MAGIC);
    if (b == NBLK - 1) {
      float lp = 0.0f, en = 0.0f;
      for (int j = 0; j < NBLK; ++j) {
        while (iload(&done[j]) != DONE_MAGIC) __builtin_amdgcn_s_sleep(1);
        lp += fload(&part[2 * j]);
        en += fload(&part[2 * j + 1]);
      }
      out[60] = lp;
      out[61] = en;
    }
  }
}

extern "C" void kernel_launch(void* const* d_in, const int* in_sizes, int n_in,
                              void* d_out, int out_size, void* d_ws, size_t ws_size,
                              hipStream_t stream) {
  const float* enc = (const float*)d_in[0];
  const float* wih = (const float*)d_in[1];
  const float* whh = (const float*)d_in[2];
  const float* bih = (const float*)d_in[3];
  const float* bhh = (const float*)d_in[4];
  const float* w1  = (const float*)d_in[5];
  const float* w2  = (const float*)d_in[6];
  const float* v   = (const float*)d_in[7];
  unsigned char* ws = (unsigned char*)d_ws;
  float* out = (float*)d_out;

  if (ws_size >= W_NEED) {
    ctrl_v13<<<dim3(64), dim3(THR), 0, stream>>>(
        enc, wih, whh, bih, bhh, w1, w2, v, ws, out);
  } else {
    ctrl_small<<<dim3(64), dim3(1024), 0, stream>>>(
        enc, wih, whh, bih, bhh, w1, w2, v, ws, out);
  }
}